// Round 7
// baseline (292.596 us; speedup 1.0000x reference)
//
#include <hip/hip_runtime.h>

#define HW    512
#define OUTW  128
#define NIMG  96                           // 32*3
#define N_HR  ((long long)NIMG*HW*HW)      // 25165824
#define N_LR  ((long long)NIMG*OUTW*OUTW)  // 1572864

#define NPIXS (NIMG*HW/1)                  // pix partial slots: one per input row = 49152
#define NLRS  (NIMG*OUTW)                  // lr partial slots: one per output row = 12288
#define HSTR  (HW*OUTW)                    // h-buffer stride per image (65536 floats)

// PyTorch bicubic kernel, a = -0.75
__device__ __forceinline__ float cubic075(float x){
    float ax = fabsf(x);
    float ax2 = ax*ax, ax3 = ax2*ax;
    const float A = -0.75f;
    float f1 = (A+2.f)*ax3 - (A+3.f)*ax2 + 1.f;
    float f2 = A*ax3 - 5.f*A*ax2 + 8.f*A*ax - 4.f*A;
    return ax <= 1.f ? f1 : (ax < 2.f ? f2 : 0.f);
}

// scale=4 antialiased window: 16 taps, dist=(k-7.5)/4, normalized.
// Shift-invariant across all output positions (verified absmax=0.0).
__device__ __forceinline__ void get_weights(float w[16]){
    float s = 0.f;
#pragma unroll
    for (int k = 0; k < 16; ++k){
        float d = ((float)k - 7.5f) * 0.25f;
        w[k] = cubic075(d);
        s += w[k];
    }
#pragma unroll
    for (int k = 0; k < 16; ++k) w[k] /= s;
}

// R7: the fused band kernel is pinned at ~84us by a per-CU MLP cap under
// high queued latency (evidence: bytes +26% (R2) and -20% (R6) both leave
// time unchanged; counted vmcnt (R4), chunk drains (R6), XCD swizzle (R5)
// all neutral; delivered BW tracks in-flight state: 4.1/3.4/2.6 TB/s for
// most/mid/least outstanding). Escape = split at the separable-filter
// boundary so each pass sits in a known-good regime:
//  k1: pix + horizontal filter, one wave per input row. No vertical halo,
//      every P/T byte read exactly once, no LDS/barriers, 49152 independent
//      waves -> m13 streaming regime (6.3 TB/s ceiling).
//  k2: vertical filter + lr, one wave per output row. Reads the 25MB
//      h-buffer (256KB/image, XCD-pinned by matching swizzle -> L2-resident,
//      ~200cy latency -> MLP cap doesn't bite).
//  k3: reduce partials.
// Workspace: 49152+12288 doubles (partials) + 25.2MB h-buffer.

__global__ __launch_bounds__(256) void k1(const float* __restrict__ pred,
                                          const float* __restrict__ tgt,
                                          double* __restrict__ partPix,
                                          float* __restrict__ hbuf){
    // XCD-pin: img = task>>9; make consecutive hw-blocks-on-one-XCD own
    // consecutive tasks so each image (128 blocks) stays on one XCD.
    const int b       = blockIdx.x;                   // 0..12287
    const int logical = ((b & 7) * 1536) + (b >> 3);  // bijective, 12288%8==0
    const int w   = threadIdx.x >> 6;
    const int l   = threadIdx.x & 63;
    const int task = (logical << 2) + w;              // 0..49151
    const int img  = task >> 9;
    const int row  = task & 511;

    float wt[16]; get_weights(wt);
    const float4* Pr = (const float4*)(pred + (size_t)img*(HW*HW) + (size_t)row*HW);
    const float4* Tr = (const float4*)(tgt  + (size_t)img*(HW*HW) + (size_t)row*HW);

    const float4 c0 = Pr[2*l], c1 = Pr[2*l+1];
    const float4 t0 = Tr[2*l], t1 = Tr[2*l+1];
    const float p0=c0.x,p1v=c0.y,p2v=c0.z,p3=c0.w,
                p4=c1.x,p5=c1.y,p6=c1.z,p7=c1.w;

    // pix term over this row (each input byte touched exactly once)
    float pix_acc = fabsf(p0-t0.x)+fabsf(p1v-t0.y)+fabsf(p2v-t0.z)+fabsf(p3-t0.w)
                  + fabsf(p4-t1.x)+fabsf(p5-t1.y)+fabsf(p6-t1.z)+fabsf(p7-t1.w);

    // horizontal halo via shuffles: cols 8l-6..8l-1 and 8l+8..8l+13
    float Lm6 = __shfl_up(p2v,1,64), Lm5 = __shfl_up(p3,1,64),
          Lm4 = __shfl_up(p4,1,64),  Lm3 = __shfl_up(p5,1,64),
          Lm2 = __shfl_up(p6,1,64),  Lm1 = __shfl_up(p7,1,64);
    float R8  = __shfl_down(p0,1,64), R9  = __shfl_down(p1v,1,64),
          R10 = __shfl_down(p2v,1,64),R11 = __shfl_down(p3,1,64),
          R12 = __shfl_down(p4,1,64), R13 = __shfl_down(p5,1,64);
    if (l == 0){ Lm6=p0; Lm5=p0; Lm4=p0; Lm3=p0; Lm2=p0; Lm1=p0; }
    if (l == 63){ R8=p7; R9=p7; R10=p7; R11=p7; R12=p7; R13=p7; }

    float w20[20] = {Lm6,Lm5,Lm4,Lm3,Lm2,Lm1,p0,p1v,p2v,p3,p4,p5,p6,p7,
                     R8,R9,R10,R11,R12,R13};
    float h0 = 0.f, h1 = 0.f;
#pragma unroll
    for (int k = 0; k < 16; ++k){
        h0 += wt[k]*w20[k];
        h1 += wt[k]*w20[k+4];
    }

    // write h-row: lane l owns out cols 2l,2l+1
    ((float2*)(hbuf + (size_t)img*HSTR + (size_t)row*OUTW))[l] = make_float2(h0, h1);

    // intra-wave pix reduction, one slot per wave (bijective, all written)
#pragma unroll
    for (int off = 32; off > 0; off >>= 1)
        pix_acc += __shfl_down(pix_acc, off, 64);
    if (l == 0) partPix[task] = (double)pix_acc;
}

__global__ __launch_bounds__(256) void k2(const float* __restrict__ hbuf,
                                          const float* __restrict__ lr,
                                          double* __restrict__ partLr){
    const int b       = blockIdx.x;                  // 0..3071
    const int logical = ((b & 7) * 384) + (b >> 3);  // bijective, 3072%8==0
    const int w   = threadIdx.x >> 6;
    const int l   = threadIdx.x & 63;
    const int task = (logical << 2) + w;             // 0..12287
    const int img  = task >> 7;                      // matches k1's img->XCD pin
    const int o    = task & 127;                     // output row

    float wt[16]; get_weights(wt);
    const float* base = hbuf + (size_t)img*HSTR;

    float a0 = 0.f, a1 = 0.f;
#pragma unroll
    for (int k = 0; k < 16; ++k){
        const int r = min(HW-1, max(0, 4*o - 6 + k));   // replicate border
        const float2 hv = ((const float2*)(base + (size_t)r*OUTW))[l];
        a0 += wt[k]*hv.x;
        a1 += wt[k]*hv.y;
    }

    const float2 lv = ((const float2*)(lr + (size_t)img*(OUTW*OUTW) + (size_t)o*OUTW))[l];
    float lr_acc = fabsf(a0-lv.x) + fabsf(a1-lv.y);

#pragma unroll
    for (int off = 32; off > 0; off >>= 1)
        lr_acc += __shfl_down(lr_acc, off, 64);
    if (l == 0) partLr[task] = (double)lr_acc;
}

__global__ __launch_bounds__(256) void k3(const double* __restrict__ partPix,
                                          const double* __restrict__ partLr,
                                          float* __restrict__ out){
    const int t = threadIdx.x;
    double v1 = 0.0, v2 = 0.0;
    for (int i = t; i < NPIXS; i += 256) v1 += partPix[i];
    for (int i = t; i < NLRS;  i += 256) v2 += partLr[i];
#pragma unroll
    for (int off = 32; off > 0; off >>= 1){
        v1 += __shfl_down(v1, off, 64);
        v2 += __shfl_down(v2, off, 64);
    }
    __shared__ double s1[4], s2[4];
    const int lane = t & 63, wid = t >> 6;
    if (lane == 0){ s1[wid] = v1; s2[wid] = v2; }
    __syncthreads();
    if (t == 0){
        double S1 = s1[0]+s1[1]+s1[2]+s1[3];
        double S2 = s2[0]+s2[1]+s2[2]+s2[3];
        float pix     = (float)(S1 / (double)N_HR);
        float lr_term = (float)(S2 / (double)N_LR);
        float pair    = 0.f;
        float consist = 1.0f * lr_term + 1.0f * pair;   // LAM_LR, LAM_PAIR
        float total   = pix + 0.1f * consist;           // LAM_CONSIST
        out[0] = total; out[1] = pix; out[2] = consist; out[3] = lr_term; out[4] = pair;
    }
}

extern "C" void kernel_launch(void* const* d_in, const int* in_sizes, int n_in,
                              void* d_out, int out_size, void* d_ws, size_t ws_size,
                              hipStream_t stream){
    const float* pred = (const float*)d_in[0];
    const float* tgt  = (const float*)d_in[1];
    const float* lrr  = (const float*)d_in[2];
    float* out = (float*)d_out;

    // workspace layout: [partPix: 49152 dbl][partLr: 12288 dbl][hbuf: 25.2MB fp32]
    double* partPix = (double*)d_ws;
    double* partLr  = partPix + NPIXS;
    float*  hbuf    = (float*)(partLr + NLRS);   // byte offset 491520, 4KB-aligned

    k1<<<NIMG*HW/4, 256, 0, stream>>>(pred, tgt, partPix, hbuf);
    k2<<<NIMG*OUTW/4, 256, 0, stream>>>(hbuf, lrr, partLr);
    k3<<<1, 256, 0, stream>>>(partPix, partLr, out);
}